// Round 4
// baseline (7543.691 us; speedup 1.0000x reference)
//
#include <hip/hip_runtime.h>
#include <hip/hip_fp16.h>

#define B_ 32
#define T_ 4096
#define F_ 128
#define C_ 256
#define K_ 128
#define FC_ 384

typedef __attribute__((ext_vector_type(2))) _Float16 h2v;
typedef __attribute__((ext_vector_type(8))) _Float16 h8v;
typedef __attribute__((ext_vector_type(4))) float f4v;

#define MFMAH(a,b,c) __builtin_amdgcn_mfma_f32_16x16x32_f16((a),(b),(c),0,0,0)
#define FDOT2(h,w,acc) __builtin_amdgcn_fdot2((h),(w),(acc),false)

// ---- workspace layout (bytes) ----
#define WS_WSCAN 0u        // gw16[256][256] + aw16[256][256] fp16 = 262144
#define WS_W1F   262144u   // 12288 B-frags * 16B = 196608
#define WS_OWF   458752u   // 4096 * 16 = 65536
#define WS_BIAS1 524288u   // 768 * 4 = 3072
#define WS_CARRY 527360u   // n,d,h,am : 4 * 8192 f32 = 131072
#define WS_DYN   658432u   // pre chunk (49152*Tc B) then hall chunk (16384*Tc B)

__device__ __forceinline__ float ftanh(float x){
  float xc = fminf(fmaxf(x,-9.02f),9.02f);
  float e = __expf(2.0f*xc);
  return 1.0f - 2.0f*__builtin_amdgcn_rcpf(e+1.0f);
}

// ---------------- weight packing (all fp16) ----------------
// scan weights: plain [c][k] rows. ph1/ph3 weights: MFMA B-frag layout
// (16x16x32): lane l, reg j holds B[k = kc*32 + (l>>4)*8 + j][n = 16*nt + (l&15)]
__global__ __launch_bounds__(256) void pack_kernel(
    const float* __restrict__ g_w, const float* __restrict__ u_w, const float* __restrict__ a_w,
    const float* __restrict__ g_b, const float* __restrict__ u_b, const float* __restrict__ o_w,
    char* __restrict__ ws)
{
  int id = blockIdx.x*256 + threadIdx.x;
  _Float16* gw16 = (_Float16*)(ws + WS_WSCAN);            // [256][256]
  _Float16* aw16 = gw16 + 65536;                          // [256][256]
  _Float16* w1f  = (_Float16*)(ws + WS_W1F);
  _Float16* owf  = (_Float16*)(ws + WS_OWF);
  float* bias1   = (float*)(ws + WS_BIAS1);
  if (id < 8192){
    int c = id>>5, k0 = (id&31)*8;
    #pragma unroll
    for (int j=0;j<8;++j) gw16[c*256+k0+j] = (_Float16)g_w[c*FC_ + F_ + k0 + j];
  } else if (id < 16384){
    int id1 = id - 8192;
    int c = id1>>5, k0 = (id1&31)*8;
    #pragma unroll
    for (int j=0;j<8;++j) aw16[c*256+k0+j] = (_Float16)a_w[c*FC_ + F_ + k0 + j];
  } else if (id < 16384+12288){
    // ph1 weights rows n: [0,256)=u_w, [256,512)=g_w x-part, [512,768)=a_w x-part
    int id2 = id - 16384;
    int l = id2 & 63, kc = (id2>>6)&3, nt = id2>>8;
    int n = nt*16 + (l&15);
    int kb = kc*32 + (l>>4)*8;
    #pragma unroll
    for (int j=0;j<8;++j){
      int k = kb + j;
      float v = (n < 256) ? u_w[n*F_ + k]
              : (n < 512) ? g_w[(n-256)*FC_ + k]
                          : a_w[(n-512)*FC_ + k];
      w1f[id2*8+j] = (_Float16)v;
    }
  } else if (id < 16384+12288+4096){
    int id3 = id - (16384+12288);
    int l = id3 & 63, kc = (id3>>6)&7, nt = id3>>9;
    int n = nt*16 + (l&15);
    int kb = kc*32 + (l>>4)*8;
    #pragma unroll
    for (int j=0;j<8;++j)
      owf[id3*8+j] = (_Float16)o_w[n*C_ + kb + j];
  } else if (id < 16384+12288+4096+768){
    int i = id - (16384+12288+4096);
    bias1[i] = (i<256) ? u_b[i] : (i<512 ? g_b[i-256] : 0.0f);
  }
}

// ---------------- init: carry <- initial state ----------------
__global__ __launch_bounds__(256) void init_kernel(
    const float* __restrict__ n0, const float* __restrict__ d0,
    const float* __restrict__ h0, const float* __restrict__ am0, char* __restrict__ ws)
{
  int id = blockIdx.x*256 + threadIdx.x;   // 8192
  float* c = (float*)(ws + WS_CARRY);
  c[id]        = n0[id];
  c[8192+id]   = d0[id];
  c[16384+id]  = h0[id];
  c[24576+id]  = am0[id];
}

// ---------------- ph1: pre = x @ [u_w; g_w_x; a_w_x]^T + bias (fp16, chunk-local) --------
__global__ __launch_bounds__(256) void ph1_kernel(const float* __restrict__ x, char* __restrict__ ws,
                                                  int t0, int Tc, int lgT16)
{
  const h8v* w1f = (const h8v*)(ws + WS_W1F);
  const float* bias1 = (const float*)(ws + WS_BIAS1);
  _Float16* pre = (_Float16*)(ws + WS_DYN);
  int tid = threadIdx.x;
  int wv = tid>>6, l = tid&63, q = l>>4, col = l&15;
  int wid = blockIdx.x*4 + wv;
  int b  = wid >> lgT16;
  int tb = (wid & ((1<<lgT16)-1))*16;
  // A-frag: lane holds x[b][t0+tb+(l&15)][kc*32 + q*8 + j]
  h8v af[4];
  const float* xr = x + ((size_t)b*T_ + t0 + tb + col)*F_ + q*8;
  #pragma unroll
  for (int kc=0;kc<4;++kc){
    const float* p = xr + kc*32;
    float4 p0 = *(const float4*)(p);
    float4 p1 = *(const float4*)(p+4);
    h8v a;
    a[0]=(_Float16)p0.x; a[1]=(_Float16)p0.y; a[2]=(_Float16)p0.z; a[3]=(_Float16)p0.w;
    a[4]=(_Float16)p1.x; a[5]=(_Float16)p1.y; a[6]=(_Float16)p1.z; a[7]=(_Float16)p1.w;
    af[kc]=a;
  }
  for (int nt=0;nt<48;++nt){
    f4v acc = {0.f,0.f,0.f,0.f};
    #pragma unroll
    for (int kc=0;kc<4;++kc)
      acc = MFMAH(af[kc], w1f[(nt*4+kc)*64 + l], acc);
    int cg = nt*16 + col;
    float bs = bias1[cg];
    #pragma unroll
    for (int i=0;i<4;++i){
      int rl = tb + q*4 + i;                 // D: row = (l>>4)*4 + i
      pre[(size_t)(b*Tc + rl)*768 + cg] = (_Float16)(acc[i] + bs);
    }
  }
}

// ---------------- scan: sequential recurrence, VALU fdot2 path ----------------
// 32 blocks x 256 threads (4 waves, 1 wave/SIMD). Each lane owns channel c = tid:
// g[c] and a[c] computed as register-resident fp16 dot products over h (LDS broadcast).
// No MFMA, no M-replication waste: 512 FLOP/cyc/CU vs 16x-replicated MFMA's effective 211.
__global__ __launch_bounds__(256,1) void scan_kernel(char* __restrict__ ws, int Tc)
{
  __shared__ __align__(16) _Float16 hls[2][256];
  const h8v* gwp = (const h8v*)(ws + WS_WSCAN);            // [256][32]
  const h8v* awp = gwp + 256*32;
  const _Float16* preh = (const _Float16*)(ws + WS_DYN);
  _Float16* hall = (_Float16*)(ws + WS_DYN + 49152u*(unsigned)Tc);
  float* carry = (float*)(ws + WS_CARRY);
  int c = threadIdx.x;
  int b = blockIdx.x;

  // resident weights: this channel's g and a rows, 32+32 h8v = 256 VGPRs
  h8v wg[32], wa[32];
  #pragma unroll
  for (int kk=0;kk<32;++kk){ wg[kk] = gwp[c*32+kk]; wa[kk] = awp[c*32+kk]; }

  int gi = b*C_ + c;
  float cn = carry[gi], cd = carry[8192+gi], cm = carry[24576+gi];
  hls[0][c] = (_Float16)carry[16384+gi];
  __syncthreads();

  const size_t prb = (size_t)b*Tc*768;
  _Float16* hrow = hall + (size_t)b*Tc*C_ + c;

  // prefetch pre for t=0,1 (2-deep pipeline hides HBM latency)
  _Float16 su[2], sg[2], sa[2];
  su[0]=preh[prb + c];       sg[0]=preh[prb + 256+c];       sa[0]=preh[prb + 512+c];
  su[1]=preh[prb + 768+c];   sg[1]=preh[prb + 768+256+c];   sa[1]=preh[prb + 768+512+c];

  float hv = 0.f;
  #pragma unroll 1
  for (int t=0;t<Tc;++t){
    int cur = t & 1;
    const h8v* hp = (const h8v*)hls[cur];
    float fu = (float)su[cur], fg = (float)sg[cur], fa = (float)sa[cur];
    {
      int nxt = (t+2 < Tc) ? t+2 : t;
      size_t o = prb + (size_t)nxt*768;
      su[cur]=preh[o + c]; sg[cur]=preh[o + 256+c]; sa[cur]=preh[o + 512+c];
    }
    // g[c], a[c]: 256-long fp16 dots, 8 independent accumulator chains (depth 32)
    float g0=fg, g1=0.f, g2=0.f, g3=0.f;
    float a0=fa, a1=0.f, a2=0.f, a3=0.f;
    #pragma unroll
    for (int kk=0;kk<32;++kk){
      h8v h8 = hp[kk];                        // ds_read_b128 broadcast
      h2v h01; h01[0]=h8[0]; h01[1]=h8[1];
      h2v h23; h23[0]=h8[2]; h23[1]=h8[3];
      h2v h45; h45[0]=h8[4]; h45[1]=h8[5];
      h2v h67; h67[0]=h8[6]; h67[1]=h8[7];
      h8v w = wg[kk];
      h2v w01; w01[0]=w[0]; w01[1]=w[1];
      h2v w23; w23[0]=w[2]; w23[1]=w[3];
      h2v w45; w45[0]=w[4]; w45[1]=w[5];
      h2v w67; w67[0]=w[6]; w67[1]=w[7];
      g0 = FDOT2(h01,w01,g0); g1 = FDOT2(h23,w23,g1);
      g2 = FDOT2(h45,w45,g2); g3 = FDOT2(h67,w67,g3);
      h8v v = wa[kk];
      h2v v01; v01[0]=v[0]; v01[1]=v[1];
      h2v v23; v23[0]=v[2]; v23[1]=v[3];
      h2v v45; v45[0]=v[4]; v45[1]=v[5];
      h2v v67; v67[0]=v[6]; v67[1]=v[7];
      a0 = FDOT2(h01,v01,a0); a1 = FDOT2(h23,v23,a1);
      a2 = FDOT2(h45,v45,a2); a3 = FDOT2(h67,v67,a3);
    }
    float g = (g0+g1)+(g2+g3);
    float a = (a0+a1)+(a2+a3);

    float z = fu * ftanh(g);
    float anew = fmaxf(cm,a);
    float dmin = fminf(cm,a);
    float e = __expf(dmin-anew);     // one of exp_diff/exp_scaled is exp(0)=1
    bool ge = (a>=cm);
    float ed = ge? e : 1.0f;
    float es = ge? 1.0f : e;
    cn = cn*ed + z*es;
    cd = fmaf(cd,ed,es);
    hv = ftanh(cn*__builtin_amdgcn_rcpf(cd));
    cm = anew;
    _Float16 hh = (_Float16)hv;
    hls[cur^1][c] = hh;              // next step's h
    hrow[(size_t)t*C_] = hh;         // for output GEMM
    __syncthreads();
  }
  // write back carry
  carry[gi] = cn; carry[8192+gi] = cd; carry[16384+gi] = hv; carry[24576+gi] = cm;
}

// ---------------- ph3: outs = h @ o_w^T + o_b  (one wave per (b, 16-step tile)) --------
__global__ __launch_bounds__(256) void ph3_kernel(const float* __restrict__ o_b,
                                                  char* __restrict__ ws, float* __restrict__ out,
                                                  int t0, int Tc, int lgT16)
{
  const h8v* owf = (const h8v*)(ws + WS_OWF);
  const _Float16* hall = (const _Float16*)(ws + WS_DYN + 49152u*(unsigned)Tc);
  int tid = threadIdx.x;
  int wv = tid>>6, l = tid&63, q=l>>4, col=l&15;
  int wid = blockIdx.x*4 + wv;
  int bb = wid >> lgT16;
  int tt = (wid & ((1<<lgT16)-1))*16;
  // A[m=col][k] = h[b=bb][t=tt+col][k]
  const _Float16* src = hall + ((size_t)bb*Tc + tt)*C_;
  h8v af[8];
  #pragma unroll
  for (int kc=0;kc<8;++kc)
    af[kc] = *(const h8v*)(src + (size_t)col*C_ + kc*32 + q*8);
  #pragma unroll
  for (int nt=0;nt<8;++nt){
    f4v acc={0.f,0.f,0.f,0.f};
    #pragma unroll
    for (int kc=0;kc<8;++kc)
      acc = MFMAH(af[kc], owf[(nt*8+kc)*64 + l], acc);
    int k = nt*16+col;
    float bs = o_b[k];
    #pragma unroll
    for (int i=0;i<4;++i)
      out[((size_t)bb*T_ + t0 + tt + q*4 + i)*K_ + k] = acc[i] + bs;
  }
}

// ---------------- finalize: final states -> out tail ----------------
__global__ __launch_bounds__(256) void fin_kernel(char* __restrict__ ws, float* __restrict__ out)
{
  int id = blockIdx.x*256 + threadIdx.x;   // 8192
  const float* c = (const float*)(ws + WS_CARRY);
  size_t ob = (size_t)B_*T_*K_;
  out[ob + id]         = c[id];            // n_t
  out[ob + 8192 + id]  = c[8192+id];       // d_t
  out[ob + 16384 + id] = c[16384+id];      // h_t
  out[ob + 24576 + id] = c[24576+id];      // a_new
}

extern "C" void kernel_launch(void* const* d_in, const int* in_sizes, int n_in,
                              void* d_out, int out_size, void* d_ws, size_t ws_size,
                              hipStream_t stream)
{
  const float* x   = (const float*)d_in[0];
  const float* n0  = (const float*)d_in[1];
  const float* d0  = (const float*)d_in[2];
  const float* h0  = (const float*)d_in[3];
  const float* am0 = (const float*)d_in[4];
  const float* g_w = (const float*)d_in[5];
  const float* g_b = (const float*)d_in[6];
  const float* u_w = (const float*)d_in[7];
  const float* u_b = (const float*)d_in[8];
  const float* a_w = (const float*)d_in[9];
  const float* o_w = (const float*)d_in[10];
  const float* o_b = (const float*)d_in[11];
  float* out = (float*)d_out;
  char* ws = (char*)d_ws;

  // pick largest power-of-two time chunk Tc that fits: fixed + (49152+16384)*Tc bytes
  unsigned Tc = 4096;
  while (Tc > 64 && (size_t)WS_DYN + 65536ull*Tc > ws_size) Tc >>= 1;
  if ((size_t)WS_DYN + 65536ull*Tc > ws_size) return;  // ws hopeless -> zeros (diagnosable)
  int lgTc  = __builtin_ctz(Tc);
  int lgT16 = lgTc - 4;
  int nch   = T_ / (int)Tc;

  hipLaunchKernelGGL(pack_kernel, dim3(131), dim3(256), 0, stream,
                     g_w, u_w, a_w, g_b, u_b, o_w, ws);
  hipLaunchKernelGGL(init_kernel, dim3(32), dim3(256), 0, stream,
                     n0, d0, h0, am0, ws);
  for (int c0=0; c0<nch; ++c0){
    int t0 = c0*(int)Tc;
    hipLaunchKernelGGL(ph1_kernel, dim3(B_*(int)Tc/64), dim3(256), 0, stream,
                       x, ws, t0, (int)Tc, lgT16);
    hipLaunchKernelGGL(scan_kernel, dim3(B_), dim3(256), 0, stream,
                       ws, (int)Tc);
    hipLaunchKernelGGL(ph3_kernel, dim3(B_*(int)Tc/64), dim3(256), 0, stream,
                       o_b, ws, out, t0, (int)Tc, lgT16);
  }
  hipLaunchKernelGGL(fin_kernel, dim3(32), dim3(256), 0, stream, ws, out);
}